// Round 2
// baseline (184.425 us; speedup 1.0000x reference)
//
#include <hip/hip_runtime.h>
#include <hip/hip_cooperative_groups.h>
#include <hip/hip_bf16.h>
#include <math.h>

namespace cg = cooperative_groups;

// VariableSelectionNetwork — MI355X (gfx950), round 12
//
// Identity: scorer LayerNorm over a size-1 axis => output == sc_ln_b, so
// softmax weights W[f] = softmax(sc_ln_b) are constant and the scorer GRN is
// dead code. Remaining: mix = x @ WT^T + c ; post-GRN (3x 256x256) ; gated
// skip ; LayerNorm(256).
//
// Round 12: round-10 prep + round-10 main, UNMODIFIED, in ONE cooperative
// launch with a grid.sync() between them.
//   Post-mortem r11: fp32 direct B-loads + fp32 prefetch buffers spilled
//   (at 1 wave/SIMD nothing hides scratch), kernel part 26.6 -> 40.3 us.
//   Reverted entirely. The only change vs round 10 (best: kernel part
//   26.6 us) is removing the second launch + inter-kernel gap. Weights are
//   still pre-swizzled bf16 in ws; GEMM core is byte-identical to r10.

typedef __bf16 bf16;
typedef __bf16 bf16x8 __attribute__((ext_vector_type(8)));
typedef __bf16 bf16x4 __attribute__((ext_vector_type(4)));
typedef float f32x4 __attribute__((ext_vector_type(4)));

#define NTOK 8192
#define D_   256
#define F_   32

// ws layout (bytes)
#define OFF_C      512       // 256 f32
#define OFF_WPROJT 2048      // WT[n][f] bf16 (fragment-coalesced), 16 KB
#define OFF_FC1    32768     // swizzled bf16, 128 KB each
#define OFF_FC2    163840
#define OFF_GATE   294912

// Swizzled layout: elem = j*4096 + ks*512 + lm*32 + lq*8 + e
//   == W[row = j*16+lm][col = ks*32 + lq*8 + e]; a wave's (j,ks) fragment
// load is one contiguous 1 KB segment.

__global__ __launch_bounds__(256, 1) void vsn_coop(
    const float* __restrict__ x,
    const float* __restrict__ proj_w, const float* __restrict__ proj_b,
    const float* __restrict__ sc_ln_b,
    const float* __restrict__ w1, const float* __restrict__ fc1_b,
    const float* __restrict__ w2, const float* __restrict__ fc2_b,
    const float* __restrict__ w3, const float* __restrict__ gate_b,
    const float* __restrict__ ln_g, const float* __restrict__ ln_b,
    float* __restrict__ wsC, bf16* __restrict__ wsWT,
    bf16* __restrict__ o1, bf16* __restrict__ o2, bf16* __restrict__ o3,
    float* __restrict__ out)
{
  __shared__ bf16  sAct[2][32][264];   // ping-pong bf16 activations (A operand)
  __shared__ float sY[32][260];        // fp32 y2 for LayerNorm

  const int tid = threadIdx.x;
  const int blk = blockIdx.x;

  // ================= prep phase (exact round-10 vsn_prep) =================
  if (blk < 48) {
    int g = blk * 256 + tid;                  // 0..12287 half-chunks (16 floats)
    int m = g >> 12;                          // matrix 0..2
    int c = g & 4095;                         // row = c>>4, ks = (c>>1)&7, half = c&1
    const float* src = (m == 0) ? w1 : (m == 1) ? w2 : w3;
    bf16* dst = (m == 0) ? o1 : (m == 1) ? o2 : o3;
    int row = c >> 4, ks = (c >> 1) & 7, half = c & 1;
    int j = row >> 4, lmr = row & 15;
    const float* sp = src + row * 256 + ks * 32 + half * 16;  // 16 contig floats
    bf16* dp = dst + j * 4096 + ks * 512 + lmr * 32 + half * 16;
    #pragma unroll
    for (int q = 0; q < 2; q++) {
      float4 a = ((const float4*)sp)[2 * q];
      float4 b = ((const float4*)sp)[2 * q + 1];
      bf16x8 v = {(bf16)a.x, (bf16)a.y, (bf16)a.z, (bf16)a.w,
                  (bf16)b.x, (bf16)b.y, (bf16)b.z, (bf16)b.w};
      *(bf16x8*)(dp + q * 8) = v;
    }
  } else if (blk == 48) {
    const int d = tid;
    float wv[F_];
    float mx = -3.0e38f;
    #pragma unroll
    for (int f = 0; f < F_; f++) { wv[f] = sc_ln_b[f]; mx = fmaxf(mx, wv[f]); }
    float se = 0.0f;
    #pragma unroll
    for (int f = 0; f < F_; f++) { wv[f] = __expf(wv[f] - mx); se += wv[f]; }
    float inv = 1.0f / se;
    float acc = 0.0f;
    #pragma unroll
    for (int f = 0; f < F_; f++) {
      float wf = wv[f] * inv;
      acc += wf * proj_b[f * D_ + d];
      wsWT[d * F_ + f] = (bf16)(wf * proj_w[f * D_ + d]);
    }
    wsC[d] = acc;
  }

  __threadfence();            // device-scope release of ws writes
  cg::this_grid().sync();     // all 256 blocks: prep results visible

  // ================= main phase (exact round-10 vsn_main) =================
  const int w    = tid >> 6;
  const int lane = tid & 63;
  const int lm   = lane & 15;
  const int lq   = lane >> 4;
  const int j0   = w * 4;
  const int tok0 = blk * 32;

  const bf16* WT   = wsWT;
  const bf16* FC1  = o1;
  const bf16* FC2  = o2;
  const bf16* GATE = o3;

  // ---- phase 1: mix = x @ WT^T + c (K=32); 2 M-tiles share each B ----
  bf16x4 mixh[2][4];
  {
    bf16x8 a[2];
    #pragma unroll
    for (int t = 0; t < 2; t++) {
      const float* xp = x + (size_t)(tok0 + t * 16 + lm) * F_ + lq * 8;
      float4 x0 = *(const float4*)xp;
      float4 x1 = *(const float4*)(xp + 4);
      bf16x8 av = {(bf16)x0.x, (bf16)x0.y, (bf16)x0.z, (bf16)x0.w,
                   (bf16)x1.x, (bf16)x1.y, (bf16)x1.z, (bf16)x1.w};
      a[t] = av;
    }
    #pragma unroll
    for (int jj = 0; jj < 4; jj++) {
      int n = (j0 + jj) * 16 + lm;
      bf16x8 b = *(const bf16x8*)(WT + n * F_ + lq * 8);   // 1KB/wave contig
      float cv = wsC[n];
      #pragma unroll
      for (int t = 0; t < 2; t++) {
        f32x4 acc = {cv, cv, cv, cv};
        acc = __builtin_amdgcn_mfma_f32_16x16x32_bf16(a[t], b, acc, 0, 0, 0);
        bf16x4 mh = {(bf16)acc[0], (bf16)acc[1], (bf16)acc[2], (bf16)acc[3]};
        mixh[t][jj] = mh;
        #pragma unroll
        for (int r = 0; r < 4; r++) sAct[0][t * 16 + lq * 4 + r][n] = mh[r];
      }
    }
  }
  __syncthreads();

  // generic phase: read A-tiles from sAct[src], gemm vs swizzled W, epilogue
  auto gemmPhase = [&](int src, const bf16* __restrict__ W, auto&& epi) {
    bf16x8 af[2][8];
    #pragma unroll
    for (int t = 0; t < 2; t++)
      #pragma unroll
      for (int ks = 0; ks < 8; ks++)
        af[t][ks] = *(const bf16x8*)(&sAct[src][t * 16 + lm][ks * 32 + lq * 8]);
    const bf16* base = W + j0 * 4096 + lm * 32 + lq * 8;
    bf16x8 bb[8];
    #pragma unroll
    for (int ks = 0; ks < 8; ks++)
      bb[ks] = *(const bf16x8*)(base + ks * 512);          // 1KB/wave contig
    #pragma unroll
    for (int jj = 0; jj < 4; jj++) {
      bf16x8 bn[8];
      if (jj < 3) {
        const bf16* nb = base + (jj + 1) * 4096;
        #pragma unroll
        for (int ks = 0; ks < 8; ks++)
          bn[ks] = *(const bf16x8*)(nb + ks * 512);
      }
      f32x4 acc0 = {0.f, 0.f, 0.f, 0.f}, acc1 = {0.f, 0.f, 0.f, 0.f};
      #pragma unroll
      for (int ks = 0; ks < 8; ks++) {
        acc0 = __builtin_amdgcn_mfma_f32_16x16x32_bf16(af[0][ks], bb[ks], acc0, 0, 0, 0);
        acc1 = __builtin_amdgcn_mfma_f32_16x16x32_bf16(af[1][ks], bb[ks], acc1, 0, 0, 0);
      }
      epi(jj, acc0, acc1);
      if (jj < 3) {
        #pragma unroll
        for (int ks = 0; ks < 8; ks++) bb[ks] = bn[ks];
      }
    }
  };

  // ---- phase 2: h1 = elu(mix @ fc1^T + b1) -> sAct[1] ----
  gemmPhase(0, FC1, [&](int jj, f32x4& a0, f32x4& a1) {
    int n = (j0 + jj) * 16 + lm;
    float bias = fc1_b[n];
    #pragma unroll
    for (int r = 0; r < 4; r++) {
      float v0 = a0[r] + bias;
      v0 = (v0 > 0.0f) ? v0 : (__expf(v0) - 1.0f);
      sAct[1][lq * 4 + r][n] = (bf16)v0;
      float v1 = a1[r] + bias;
      v1 = (v1 > 0.0f) ? v1 : (__expf(v1) - 1.0f);
      sAct[1][16 + lq * 4 + r][n] = (bf16)v1;
    }
  });
  __syncthreads();

  // ---- phase 3: h2 = h1 @ fc2^T + b2 -> sAct[0], keep packed regs ----
  bf16x4 h2h[2][4];
  gemmPhase(1, FC2, [&](int jj, f32x4& a0, f32x4& a1) {
    int n = (j0 + jj) * 16 + lm;
    float bias = fc2_b[n];
    bf16x4 h0, h1v;
    #pragma unroll
    for (int r = 0; r < 4; r++) {
      h0[r]  = (bf16)(a0[r] + bias);
      h1v[r] = (bf16)(a1[r] + bias);
      sAct[0][lq * 4 + r][n] = h0[r];
      sAct[0][16 + lq * 4 + r][n] = h1v[r];
    }
    h2h[0][jj] = h0;
    h2h[1][jj] = h1v;
  });
  __syncthreads();

  // ---- phase 4: gate, gated skip -> sY ----
  gemmPhase(0, GATE, [&](int jj, f32x4& a0, f32x4& a1) {
    int n = (j0 + jj) * 16 + lm;
    float bias = gate_b[n];
    #pragma unroll
    for (int r = 0; r < 4; r++) {
      float s0 = a0[r] + bias;
      float g0 = 1.0f / (1.0f + __expf(-s0));
      sY[lq * 4 + r][n] = g0 * (float)h2h[0][jj][r] + (1.0f - g0) * (float)mixh[0][jj][r];
      float s1 = a1[r] + bias;
      float g1 = 1.0f / (1.0f + __expf(-s1));
      sY[16 + lq * 4 + r][n] = g1 * (float)h2h[1][jj][r] + (1.0f - g1) * (float)mixh[1][jj][r];
    }
  });
  __syncthreads();

  // ---- phase 5: LayerNorm(256); 16-lane group handles 2 tokens ----
  const float inv_d = 1.0f / 256.0f;
  #pragma unroll
  for (int rep = 0; rep < 2; rep++) {
    const int t = (w * 4 + lq) * 2 + rep;
    float4 yv[4];
    #pragma unroll
    for (int i = 0; i < 4; i++)
      yv[i] = *(const float4*)(&sY[t][lm * 4 + i * 64]);
    float s = 0.0f;
    #pragma unroll
    for (int i = 0; i < 4; i++) s += yv[i].x + yv[i].y + yv[i].z + yv[i].w;
    #pragma unroll
    for (int off = 1; off < 16; off <<= 1) s += __shfl_xor(s, off);
    float mean = s * inv_d;
    float q = 0.0f;
    #pragma unroll
    for (int i = 0; i < 4; i++) {
      float d0 = yv[i].x - mean, d1 = yv[i].y - mean,
            d2 = yv[i].z - mean, d3 = yv[i].w - mean;
      q += d0 * d0 + d1 * d1 + d2 * d2 + d3 * d3;
    }
    #pragma unroll
    for (int off = 1; off < 16; off <<= 1) q += __shfl_xor(q, off);
    float rstd = rsqrtf(q * inv_d + 1e-5f);
    #pragma unroll
    for (int i = 0; i < 4; i++) {
      int n = lm * 4 + i * 64;
      float4 gv = *(const float4*)(ln_g + n);
      float4 bv = *(const float4*)(ln_b + n);
      float4 o;
      o.x = (yv[i].x - mean) * rstd * gv.x + bv.x;
      o.y = (yv[i].y - mean) * rstd * gv.y + bv.y;
      o.z = (yv[i].z - mean) * rstd * gv.z + bv.z;
      o.w = (yv[i].w - mean) * rstd * gv.w + bv.w;
      *(float4*)(out + (size_t)(tok0 + t) * D_ + n) = o;
    }
  }
}

extern "C" void kernel_launch(void* const* d_in, const int* in_sizes, int n_in,
                              void* d_out, int out_size, void* d_ws, size_t ws_size,
                              hipStream_t stream) {
  (void)in_sizes; (void)n_in; (void)ws_size; (void)out_size;
  const float* x      = (const float*)d_in[0];
  const float* proj_w = (const float*)d_in[1];
  const float* proj_b = (const float*)d_in[2];
  const float* sclnb  = (const float*)d_in[12];
  const float* fc1w   = (const float*)d_in[13];
  const float* fc1b   = (const float*)d_in[14];
  const float* fc2w   = (const float*)d_in[15];
  const float* fc2b   = (const float*)d_in[16];
  const float* gw     = (const float*)d_in[17];
  const float* gb     = (const float*)d_in[18];
  const float* lng    = (const float*)d_in[19];
  const float* lnb    = (const float*)d_in[20];

  char* ws = (char*)d_ws;
  float* wsC   = (float*)(ws + OFF_C);
  bf16*  wsWT  = (bf16*)(ws + OFF_WPROJT);
  bf16*  bFC1  = (bf16*)(ws + OFF_FC1);
  bf16*  bFC2  = (bf16*)(ws + OFF_FC2);
  bf16*  bGATE = (bf16*)(ws + OFF_GATE);
  float* outp  = (float*)d_out;

  void* args[] = {
    (void*)&x, (void*)&proj_w, (void*)&proj_b, (void*)&sclnb,
    (void*)&fc1w, (void*)&fc1b, (void*)&fc2w, (void*)&fc2b,
    (void*)&gw, (void*)&gb, (void*)&lng, (void*)&lnb,
    (void*)&wsC, (void*)&wsWT, (void*)&bFC1, (void*)&bFC2, (void*)&bGATE,
    (void*)&outp
  };
  hipLaunchCooperativeKernel((void*)vsn_coop, dim3(NTOK / 32), dim3(256),
                             args, 0, stream);
}

// Round 3
// 115.745 us; speedup vs baseline: 1.5934x; 1.5934x over previous
//
#include <hip/hip_runtime.h>
#include <hip/hip_bf16.h>
#include <math.h>

// VariableSelectionNetwork — MI355X (gfx950), round 13
//
// Identity: scorer LayerNorm over a size-1 axis => output == sc_ln_b, so
// softmax weights W[f] = softmax(sc_ln_b) are constant and the scorer GRN is
// dead code. Remaining: mix = x @ WT^T + c ; post-GRN (3x 256x256) ; gated
// skip ; LayerNorm(256).
//
// Round 13: back to the r10 two-kernel structure (r11 fusion: +14 us from
// register spill; r12 cooperative: +74 us from grid.sync — both reverted).
// One change vs r10: main grid 256 -> 512 (16 tokens/block, 4 waves).
//   Theory: at grid 256 there is exactly 1 block/CU; the 5 phase barriers
//   stall the whole CU (same-block waves are barrier-locked, which is why
//   8-wave r8 was null). 2 independent blocks/CU lets one block's MFMA
//   phases fill the other's barrier/L2 stalls. LDS 33.5 KB, VGPR ~halved.

typedef __bf16 bf16;
typedef __bf16 bf16x8 __attribute__((ext_vector_type(8)));
typedef __bf16 bf16x4 __attribute__((ext_vector_type(4)));
typedef float f32x4 __attribute__((ext_vector_type(4)));

#define NTOK 8192
#define D_   256
#define F_   32

// ws layout (bytes)
#define OFF_C      512       // 256 f32
#define OFF_WPROJT 2048      // WT[n][f] bf16 (fragment-coalesced), 16 KB
#define OFF_FC1    32768     // swizzled bf16, 128 KB each
#define OFF_FC2    163840
#define OFF_GATE   294912

// Swizzled layout: elem = j*4096 + ks*512 + lm*32 + lq*8 + e
//   == W[row = j*16+lm][col = ks*32 + lq*8 + e]; a wave's (j,ks) fragment
// load is one contiguous 1 KB segment.

// ---- prep: blocks 0..47 swizzle-convert 3 weights; block 48 softmax/WT/c ----
__global__ __launch_bounds__(256) void vsn_prep(
    const float* __restrict__ proj_w, const float* __restrict__ proj_b,
    const float* __restrict__ sc_ln_b,
    const float* __restrict__ w1, const float* __restrict__ w2,
    const float* __restrict__ w3,
    float* __restrict__ wsC, bf16* __restrict__ wsWT,
    bf16* __restrict__ o1, bf16* __restrict__ o2, bf16* __restrict__ o3)
{
  const int blk = blockIdx.x;
  if (blk < 48) {
    int g = blk * 256 + threadIdx.x;          // 0..12287 half-chunks (16 floats)
    int m = g >> 12;                          // matrix 0..2
    int c = g & 4095;                         // row = c>>4, ks = (c>>1)&7, half = c&1
    const float* src = (m == 0) ? w1 : (m == 1) ? w2 : w3;
    bf16* dst = (m == 0) ? o1 : (m == 1) ? o2 : o3;
    int row = c >> 4, ks = (c >> 1) & 7, half = c & 1;
    int j = row >> 4, lmr = row & 15;
    const float* sp = src + row * 256 + ks * 32 + half * 16;  // 16 contig floats
    bf16* dp = dst + j * 4096 + ks * 512 + lmr * 32 + half * 16;
    #pragma unroll
    for (int q = 0; q < 2; q++) {
      float4 a = ((const float4*)sp)[2 * q];
      float4 b = ((const float4*)sp)[2 * q + 1];
      bf16x8 v = {(bf16)a.x, (bf16)a.y, (bf16)a.z, (bf16)a.w,
                  (bf16)b.x, (bf16)b.y, (bf16)b.z, (bf16)b.w};
      *(bf16x8*)(dp + q * 8) = v;
    }
  } else {
    const int d = threadIdx.x;
    float wv[F_];
    float mx = -3.0e38f;
    #pragma unroll
    for (int f = 0; f < F_; f++) { wv[f] = sc_ln_b[f]; mx = fmaxf(mx, wv[f]); }
    float se = 0.0f;
    #pragma unroll
    for (int f = 0; f < F_; f++) { wv[f] = __expf(wv[f] - mx); se += wv[f]; }
    float inv = 1.0f / se;
    float acc = 0.0f;
    #pragma unroll
    for (int f = 0; f < F_; f++) {
      float wf = wv[f] * inv;
      acc += wf * proj_b[f * D_ + d];
      wsWT[d * F_ + f] = (bf16)(wf * proj_w[f * D_ + d]);
    }
    wsC[d] = acc;
  }
}

// ---- main: 16 tokens / 4-wave block; wave w owns cols [64w, 64w+64) ----
__global__ __launch_bounds__(256, 2) void vsn_main(
    const float* __restrict__ x,
    const float* __restrict__ wsC,
    const bf16* __restrict__ WT,
    const bf16* __restrict__ FC1, const float* __restrict__ fc1_b,
    const bf16* __restrict__ FC2, const float* __restrict__ fc2_b,
    const bf16* __restrict__ GATE, const float* __restrict__ gate_b,
    const float* __restrict__ ln_g, const float* __restrict__ ln_b,
    float* __restrict__ out)
{
  __shared__ bf16  sAct[2][16][264];   // ping-pong bf16 activations (A operand)
  __shared__ float sY[16][260];        // fp32 y2 for LayerNorm

  const int tid  = threadIdx.x;
  const int w    = tid >> 6;
  const int lane = tid & 63;
  const int lm   = lane & 15;
  const int lq   = lane >> 4;
  const int j0   = w * 4;
  const int tok0 = blockIdx.x * 16;

  // ---- phase 1: mix = x @ WT^T + c (K=32) ----
  bf16x4 mixh[4];
  {
    const float* xp = x + (size_t)(tok0 + lm) * F_ + lq * 8;
    float4 x0 = *(const float4*)xp;
    float4 x1 = *(const float4*)(xp + 4);
    bf16x8 a = {(bf16)x0.x, (bf16)x0.y, (bf16)x0.z, (bf16)x0.w,
                (bf16)x1.x, (bf16)x1.y, (bf16)x1.z, (bf16)x1.w};
    #pragma unroll
    for (int jj = 0; jj < 4; jj++) {
      int n = (j0 + jj) * 16 + lm;
      bf16x8 b = *(const bf16x8*)(WT + n * F_ + lq * 8);   // 1KB/wave contig
      float cv = wsC[n];
      f32x4 acc = {cv, cv, cv, cv};
      acc = __builtin_amdgcn_mfma_f32_16x16x32_bf16(a, b, acc, 0, 0, 0);
      bf16x4 mh = {(bf16)acc[0], (bf16)acc[1], (bf16)acc[2], (bf16)acc[3]};
      mixh[jj] = mh;
      #pragma unroll
      for (int r = 0; r < 4; r++) sAct[0][lq * 4 + r][n] = mh[r];
    }
  }
  __syncthreads();

  // generic phase: read A-tiles from sAct[src], gemm vs swizzled W, epilogue
  auto gemmPhase = [&](int src, const bf16* __restrict__ W, auto&& epi) {
    bf16x8 af[8];
    #pragma unroll
    for (int ks = 0; ks < 8; ks++)
      af[ks] = *(const bf16x8*)(&sAct[src][lm][ks * 32 + lq * 8]);
    const bf16* base = W + j0 * 4096 + lm * 32 + lq * 8;
    bf16x8 bb[8];
    #pragma unroll
    for (int ks = 0; ks < 8; ks++)
      bb[ks] = *(const bf16x8*)(base + ks * 512);          // 1KB/wave contig
    #pragma unroll
    for (int jj = 0; jj < 4; jj++) {
      bf16x8 bn[8];
      if (jj < 3) {
        const bf16* nb = base + (jj + 1) * 4096;
        #pragma unroll
        for (int ks = 0; ks < 8; ks++)
          bn[ks] = *(const bf16x8*)(nb + ks * 512);
      }
      f32x4 acc = {0.f, 0.f, 0.f, 0.f};
      #pragma unroll
      for (int ks = 0; ks < 8; ks++)
        acc = __builtin_amdgcn_mfma_f32_16x16x32_bf16(af[ks], bb[ks], acc, 0, 0, 0);
      epi(jj, acc);
      if (jj < 3) {
        #pragma unroll
        for (int ks = 0; ks < 8; ks++) bb[ks] = bn[ks];
      }
    }
  };

  // ---- phase 2: h1 = elu(mix @ fc1^T + b1) -> sAct[1] ----
  gemmPhase(0, FC1, [&](int jj, f32x4& a0) {
    int n = (j0 + jj) * 16 + lm;
    float bias = fc1_b[n];
    #pragma unroll
    for (int r = 0; r < 4; r++) {
      float v0 = a0[r] + bias;
      v0 = (v0 > 0.0f) ? v0 : (__expf(v0) - 1.0f);
      sAct[1][lq * 4 + r][n] = (bf16)v0;
    }
  });
  __syncthreads();

  // ---- phase 3: h2 = h1 @ fc2^T + b2 -> sAct[0], keep packed regs ----
  bf16x4 h2h[4];
  gemmPhase(1, FC2, [&](int jj, f32x4& a0) {
    int n = (j0 + jj) * 16 + lm;
    float bias = fc2_b[n];
    bf16x4 h0;
    #pragma unroll
    for (int r = 0; r < 4; r++) {
      h0[r] = (bf16)(a0[r] + bias);
      sAct[0][lq * 4 + r][n] = h0[r];
    }
    h2h[jj] = h0;
  });
  __syncthreads();

  // ---- phase 4: gate, gated skip -> sY ----
  gemmPhase(0, GATE, [&](int jj, f32x4& a0) {
    int n = (j0 + jj) * 16 + lm;
    float bias = gate_b[n];
    #pragma unroll
    for (int r = 0; r < 4; r++) {
      float s0 = a0[r] + bias;
      float g0 = 1.0f / (1.0f + __expf(-s0));
      sY[lq * 4 + r][n] = g0 * (float)h2h[jj][r] + (1.0f - g0) * (float)mixh[jj][r];
    }
  });
  __syncthreads();

  // ---- phase 5: LayerNorm(256); each 16-lane group handles 1 token ----
  const float inv_d = 1.0f / 256.0f;
  {
    const int t = w * 4 + lq;                 // 0..15
    float4 yv[4];
    #pragma unroll
    for (int i = 0; i < 4; i++)
      yv[i] = *(const float4*)(&sY[t][lm * 4 + i * 64]);
    float s = 0.0f;
    #pragma unroll
    for (int i = 0; i < 4; i++) s += yv[i].x + yv[i].y + yv[i].z + yv[i].w;
    #pragma unroll
    for (int off = 1; off < 16; off <<= 1) s += __shfl_xor(s, off);
    float mean = s * inv_d;
    float q = 0.0f;
    #pragma unroll
    for (int i = 0; i < 4; i++) {
      float d0 = yv[i].x - mean, d1 = yv[i].y - mean,
            d2 = yv[i].z - mean, d3 = yv[i].w - mean;
      q += d0 * d0 + d1 * d1 + d2 * d2 + d3 * d3;
    }
    #pragma unroll
    for (int off = 1; off < 16; off <<= 1) q += __shfl_xor(q, off);
    float rstd = rsqrtf(q * inv_d + 1e-5f);
    #pragma unroll
    for (int i = 0; i < 4; i++) {
      int n = lm * 4 + i * 64;
      float4 gv = *(const float4*)(ln_g + n);
      float4 bv = *(const float4*)(ln_b + n);
      float4 o;
      o.x = (yv[i].x - mean) * rstd * gv.x + bv.x;
      o.y = (yv[i].y - mean) * rstd * gv.y + bv.y;
      o.z = (yv[i].z - mean) * rstd * gv.z + bv.z;
      o.w = (yv[i].w - mean) * rstd * gv.w + bv.w;
      *(float4*)(out + (size_t)(tok0 + t) * D_ + n) = o;
    }
  }
}

extern "C" void kernel_launch(void* const* d_in, const int* in_sizes, int n_in,
                              void* d_out, int out_size, void* d_ws, size_t ws_size,
                              hipStream_t stream) {
  (void)in_sizes; (void)n_in; (void)ws_size; (void)out_size;
  const float* x      = (const float*)d_in[0];
  const float* proj_w = (const float*)d_in[1];
  const float* proj_b = (const float*)d_in[2];
  const float* sclnb  = (const float*)d_in[12];
  const float* fc1w   = (const float*)d_in[13];
  const float* fc1b   = (const float*)d_in[14];
  const float* fc2w   = (const float*)d_in[15];
  const float* fc2b   = (const float*)d_in[16];
  const float* gw     = (const float*)d_in[17];
  const float* gb     = (const float*)d_in[18];
  const float* lng    = (const float*)d_in[19];
  const float* lnb    = (const float*)d_in[20];

  char* ws = (char*)d_ws;
  float* wsC   = (float*)(ws + OFF_C);
  bf16*  wsWT  = (bf16*)(ws + OFF_WPROJT);
  bf16*  bFC1  = (bf16*)(ws + OFF_FC1);
  bf16*  bFC2  = (bf16*)(ws + OFF_FC2);
  bf16*  bGATE = (bf16*)(ws + OFF_GATE);

  vsn_prep<<<49, 256, 0, stream>>>(proj_w, proj_b, sclnb, fc1w, fc2w, gw,
                                   wsC, wsWT, bFC1, bFC2, bGATE);
  vsn_main<<<NTOK / 16, 256, 0, stream>>>(x, wsC, wsWT,
                                          bFC1, fc1b, bFC2, fc2b, bGATE, gb,
                                          lng, lnb, (float*)d_out);
}